// Round 1
// baseline (424.171 us; speedup 1.0000x reference)
//
#include <hip/hip_runtime.h>
#include <hip/hip_bf16.h>

typedef __attribute__((ext_vector_type(8))) short bf16x8;
typedef __attribute__((ext_vector_type(4))) float f32x4;

constexpr int cH = 16, cD = 128, cHID = 2048, cS = 2048, cB = 2;
constexpr int cM = cB * cS;            // 4096 rows (b,s)
constexpr int cNQKV = cH * cD + 2 * cD; // 2304
constexpr float cEPS = 1.1920928955078125e-07f;

__device__ __forceinline__ unsigned short f2bf(float f) {
  union { float f; unsigned u; } v; v.f = f;
  unsigned r = v.u + 0x7fffu + ((v.u >> 16) & 1u);
  return (unsigned short)(r >> 16);
}

__device__ __forceinline__ f32x4 mfma16(bf16x8 a, bf16x8 b, f32x4 c) {
  return __builtin_amdgcn_mfma_f32_16x16x32_bf16(a, b, c, 0, 0, 0);
}

// ---------------- GEMM: C[Mx N] = A[M x K] * W[N x K]^T ----------------
// 128x128 tile, BK=32, 4 waves (2x2), each wave 64x64 = 4x4 16x16 frags.
// W selection: n-tile <16 -> W0 (row base bn*128), ==16 -> W1, ==17 -> W2.
template <bool A_BF16>
__global__ __launch_bounds__(256) void gemm128(
    const void* __restrict__ Ap,
    const float* __restrict__ W0, const float* __restrict__ W1,
    const float* __restrict__ W2,
    float* __restrict__ C, int N, int K)
{
  __shared__ unsigned short Al[128][40];
  __shared__ unsigned short Bl[128][40];
  const int t = threadIdx.x;
  const int bm = blockIdx.x, bn = blockIdx.y;
  const int lane = t & 63, w = t >> 6;
  const int wr = w >> 1, wc = w & 1;
  const int lr = t >> 3;          // 0..31
  const int lc = (t & 7) << 2;    // 0,4,..,28

  const float* Wp; long wbase;
  if (bn < 16)       { Wp = W0; wbase = (long)bn * 128; }
  else if (bn == 16) { Wp = W1; wbase = 0; }
  else               { Wp = W2; wbase = 0; }

  f32x4 acc[4][4] = {};

  for (int k0 = 0; k0 < K; k0 += 32) {
    #pragma unroll
    for (int i = 0; i < 4; ++i) {
      int r = (i << 5) + lr;
      long ga = (long)(bm * 128 + r) * K + k0 + lc;
      if (A_BF16) {
        ushort4 v = *reinterpret_cast<const ushort4*>((const unsigned short*)Ap + ga);
        *reinterpret_cast<ushort4*>(&Al[r][lc]) = v;
      } else {
        float4 v = *reinterpret_cast<const float4*>((const float*)Ap + ga);
        ushort4 p; p.x = f2bf(v.x); p.y = f2bf(v.y); p.z = f2bf(v.z); p.w = f2bf(v.w);
        *reinterpret_cast<ushort4*>(&Al[r][lc]) = p;
      }
      long gb = (wbase + r) * (long)K + k0 + lc;
      float4 vb = *reinterpret_cast<const float4*>(Wp + gb);
      ushort4 pb; pb.x = f2bf(vb.x); pb.y = f2bf(vb.y); pb.z = f2bf(vb.z); pb.w = f2bf(vb.w);
      *reinterpret_cast<ushort4*>(&Bl[r][lc]) = pb;
    }
    __syncthreads();
    bf16x8 af[4], bff[4];
    #pragma unroll
    for (int m = 0; m < 4; ++m)
      af[m] = *reinterpret_cast<const bf16x8*>(&Al[wr * 64 + m * 16 + (lane & 15)][(lane >> 4) * 8]);
    #pragma unroll
    for (int n = 0; n < 4; ++n)
      bff[n] = *reinterpret_cast<const bf16x8*>(&Bl[wc * 64 + n * 16 + (lane & 15)][(lane >> 4) * 8]);
    #pragma unroll
    for (int m = 0; m < 4; ++m)
      #pragma unroll
      for (int n = 0; n < 4; ++n)
        acc[m][n] = mfma16(af[m], bff[n], acc[m][n]);
    __syncthreads();
  }

  #pragma unroll
  for (int m = 0; m < 4; ++m) {
    int row = bm * 128 + wr * 64 + m * 16 + (lane >> 4) * 4;
    #pragma unroll
    for (int n = 0; n < 4; ++n) {
      int col = bn * 128 + wc * 64 + n * 16 + (lane & 15);
      #pragma unroll
      for (int r = 0; r < 4; ++r)
        C[(long)(row + r) * N + col] = acc[m][n][r];
    }
  }
}

// ------------- RoPE + RMSNorm epilogue on qkv rows -------------
// One block per (b,s). 4 waves; each wave 4 q-heads; wave0 also k, wave1 also v.
// Lane l holds the rotation pair (x[l], x[l+64]).
__global__ __launch_bounds__(256) void rope_norm(
    const float* __restrict__ C,      // [B*S][2304]
    const float* __restrict__ cosb,   // [S][64]
    const float* __restrict__ sinb,   // [S][64]
    unsigned short* __restrict__ Qn,  // [B][H][S][D] bf16
    unsigned short* __restrict__ Kn,  // [B][S][D]    bf16
    unsigned short* __restrict__ Vn)  // [B][S][D]    bf16
{
  const int row = blockIdx.x;              // b*S + s
  const int b = row >> 11, s = row & (cS - 1);
  const int w = threadIdx.x >> 6, lane = threadIdx.x & 63;
  const float cv = cosb[s * 64 + lane];
  const float sv = sinb[s * 64 + lane];
  const float* base = C + (long)row * cNQKV;

  #pragma unroll
  for (int i = 0; i < 4; ++i) {
    int h = w * 4 + i;
    float x1 = base[h * 128 + lane];
    float x2 = base[h * 128 + 64 + lane];
    float o1 = x1 * cv + x2 * sv;
    float o2 = x2 * cv - x1 * sv;
    float ss = o1 * o1 + o2 * o2;
    #pragma unroll
    for (int m = 1; m < 64; m <<= 1) ss += __shfl_xor(ss, m);
    float sc = rsqrtf(ss * (1.0f / 128.0f) + cEPS);
    long o = ((long)(b * cH + h) * cS + s) * cD + lane;
    Qn[o] = f2bf(o1 * sc);
    Qn[o + 64] = f2bf(o2 * sc);
  }
  if (w == 0) {
    float x1 = base[2048 + lane], x2 = base[2048 + 64 + lane];
    float o1 = x1 * cv + x2 * sv;
    float o2 = x2 * cv - x1 * sv;
    float ss = o1 * o1 + o2 * o2;
    #pragma unroll
    for (int m = 1; m < 64; m <<= 1) ss += __shfl_xor(ss, m);
    float sc = rsqrtf(ss * (1.0f / 128.0f) + cEPS);
    long o = ((long)b * cS + s) * cD + lane;
    Kn[o] = f2bf(o1 * sc);
    Kn[o + 64] = f2bf(o2 * sc);
  }
  if (w == 1) {
    long o = ((long)b * cS + s) * cD + lane;
    Vn[o] = f2bf(base[2176 + lane]);
    Vn[o + 64] = f2bf(base[2176 + 64 + lane]);
  }
}

// ------------- Flash attention (causal, MQA g=1) -------------
// Block = (qtile of 64 rows, h, b); 4 waves, wave w owns q rows q0..q0+15.
// kv tiles of 32. K in LDS linear; V in LDS transposed [d][kv]; P via per-wave LDS.
__global__ __launch_bounds__(256) void attn(
    const unsigned short* __restrict__ Qn,
    const unsigned short* __restrict__ Kn,
    const unsigned short* __restrict__ Vn,
    unsigned short* __restrict__ O)    // [B*S][H*D] bf16
{
  __shared__ unsigned short Kl[32][136];
  __shared__ unsigned short Vt[128][40];
  __shared__ unsigned short Pl[4][16][40];
  const int qt = blockIdx.x, h = blockIdx.y, b = blockIdx.z;
  const int t = threadIdx.x, w = t >> 6, lane = t & 63;
  const int q0 = qt * 64 + w * 16;
  const unsigned short* Qb = Qn + ((long)(b * cH + h) * cS) * cD;
  const unsigned short* Kb = Kn + (long)b * cS * cD;
  const unsigned short* Vb = Vn + (long)b * cS * cD;

  bf16x8 qf[4];
  #pragma unroll
  for (int kc = 0; kc < 4; ++kc)
    qf[kc] = *reinterpret_cast<const bf16x8*>(
        &Qb[(long)(q0 + (lane & 15)) * cD + kc * 32 + (lane >> 4) * 8]);

  f32x4 oacc[8] = {};
  float mrow[4], lrow[4];
  #pragma unroll
  for (int r = 0; r < 4; ++r) { mrow[r] = -1e30f; lrow[r] = 0.f; }

  const int r16 = t >> 4, cg = (t & 15) << 3;  // K staging map
  const int dv = t & 127, half = t >> 7;       // V staging map
  const int ntile = qt * 2 + 2;
  const float scale = 0.08838834764831845f;    // 1/sqrt(128)

  for (int kt = 0; kt < ntile; ++kt) {
    const int kv0 = kt * 32;
    __syncthreads();
    // stage K tile [32][128]
    #pragma unroll
    for (int i = 0; i < 2; ++i) {
      int kv = r16 + 16 * i;
      uint4 kvec = *reinterpret_cast<const uint4*>(&Kb[(long)(kv0 + kv) * cD + cg]);
      *reinterpret_cast<uint4*>(&Kl[kv][cg]) = kvec;
    }
    // stage V transposed: Vt[d][kv]; d-major coalesced loads, b128 LDS writes
    #pragma unroll
    for (int g2 = 0; g2 < 2; ++g2) {
      int kvg = half * 2 + g2;  // 0..3
      unsigned e[8];
      #pragma unroll
      for (int j = 0; j < 8; ++j)
        e[j] = Vb[(long)(kv0 + kvg * 8 + j) * cD + dv];
      uint4 pk;
      pk.x = e[0] | (e[1] << 16); pk.y = e[2] | (e[3] << 16);
      pk.z = e[4] | (e[5] << 16); pk.w = e[6] | (e[7] << 16);
      *reinterpret_cast<uint4*>(&Vt[dv][kvg * 8]) = pk;
    }
    __syncthreads();

    // QK^T for 32 kv cols
    f32x4 s0 = {}, s1 = {};
    #pragma unroll
    for (int kc = 0; kc < 4; ++kc) {
      bf16x8 k0f = *reinterpret_cast<const bf16x8*>(&Kl[lane & 15][kc * 32 + (lane >> 4) * 8]);
      bf16x8 k1f = *reinterpret_cast<const bf16x8*>(&Kl[16 + (lane & 15)][kc * 32 + (lane >> 4) * 8]);
      s0 = mfma16(qf[kc], k0f, s0);
      s1 = mfma16(qf[kc], k1f, s1);
    }

    // online softmax (per q-row; row spread over the 16-lane group)
    float alr[4];
    #pragma unroll
    for (int r = 0; r < 4; ++r) {
      int qrow = q0 + (lane >> 4) * 4 + r;
      int c0 = kv0 + (lane & 15);
      float v0 = (c0 <= qrow)      ? s0[r] * scale : -1e30f;
      float v1 = (c0 + 16 <= qrow) ? s1[r] * scale : -1e30f;
      float mc = fmaxf(v0, v1);
      #pragma unroll
      for (int m = 1; m < 16; m <<= 1) mc = fmaxf(mc, __shfl_xor(mc, m));
      float mnew = fmaxf(mrow[r], mc);
      float alpha = __expf(mrow[r] - mnew);
      float p0 = __expf(v0 - mnew);
      float p1 = __expf(v1 - mnew);
      mrow[r] = mnew;
      alr[r] = alpha;
      float ps = p0 + p1;
      #pragma unroll
      for (int m = 1; m < 16; m <<= 1) ps += __shfl_xor(ps, m);
      lrow[r] = lrow[r] * alpha + ps;
      int prow = (lane >> 4) * 4 + r;
      Pl[w][prow][lane & 15] = f2bf(p0);
      Pl[w][prow][16 + (lane & 15)] = f2bf(p1);
    }
    #pragma unroll
    for (int n = 0; n < 8; ++n)
      #pragma unroll
      for (int r = 0; r < 4; ++r)
        oacc[n][r] *= alr[r];

    // PV: P (16x32) @ V (32x128)
    bf16x8 pa = *reinterpret_cast<const bf16x8*>(&Pl[w][lane & 15][(lane >> 4) * 8]);
    #pragma unroll
    for (int n = 0; n < 8; ++n) {
      bf16x8 vf = *reinterpret_cast<const bf16x8*>(&Vt[n * 16 + (lane & 15)][(lane >> 4) * 8]);
      oacc[n] = mfma16(pa, vf, oacc[n]);
    }
  }

  #pragma unroll
  for (int r = 0; r < 4; ++r) {
    float inv = 1.0f / lrow[r];
    long row = (long)b * cS + q0 + (lane >> 4) * 4 + r;
    #pragma unroll
    for (int n = 0; n < 8; ++n)
      O[row * (long)(cH * cD) + h * cD + n * 16 + (lane & 15)] = f2bf(oacc[n][r] * inv);
  }
}

extern "C" void kernel_launch(void* const* d_in, const int* in_sizes, int n_in,
                              void* d_out, int out_size, void* d_ws, size_t ws_size,
                              hipStream_t stream) {
  const float* x    = (const float*)d_in[0];
  const float* cosb = (const float*)d_in[1];
  const float* sinb = (const float*)d_in[2];
  const float* wq   = (const float*)d_in[3];
  const float* wk   = (const float*)d_in[4];
  const float* wv   = (const float*)d_in[5];
  const float* wo   = (const float*)d_in[6];
  float* out = (float*)d_out;

  char* ws = (char*)d_ws;
  float* Cqkv        = (float*)ws;                                   // 37,748,736 B
  unsigned short* Qn = (unsigned short*)(ws + 37748736);             // 16,777,216 B
  unsigned short* Kn = (unsigned short*)(ws + 37748736 + 16777216);  //  1,048,576 B
  unsigned short* Vn = (unsigned short*)(ws + 37748736 + 16777216 + 1048576);
  unsigned short* Ob = (unsigned short*)ws;  // aliases Cqkv (dead after rope_norm)

  // 1) QKV projection: [4096 x 2048] @ [2304 x 2048]^T -> fp32
  gemm128<false><<<dim3(32, 18), 256, 0, stream>>>(x, wq, wk, wv, Cqkv, cNQKV, cHID);
  // 2) RoPE + RMSNorm -> bf16 Q/K/V in attention layouts
  rope_norm<<<dim3(cM), 256, 0, stream>>>(Cqkv, cosb, sinb, Qn, Kn, Vn);
  // 3) causal flash attention -> bf16 O [4096 x 2048]
  attn<<<dim3(32, 16, 2), 256, 0, stream>>>(Qn, Kn, Vn, Ob);
  // 4) output projection: [4096 x 2048] @ [2048 x 2048]^T -> fp32 d_out
  gemm128<true><<<dim3(32, 16), 256, 0, stream>>>(Ob, wo, wo, wo, out, 2048, cHID);
}

// Round 2
// 283.224 us; speedup vs baseline: 1.4977x; 1.4977x over previous
//
#include <hip/hip_runtime.h>
#include <hip/hip_bf16.h>

typedef __attribute__((ext_vector_type(8))) short bf16x8;
typedef __attribute__((ext_vector_type(4))) float f32x4;

constexpr int cH = 16, cD = 128, cHID = 2048, cS = 2048, cB = 2;
constexpr int cM = cB * cS;            // 4096 rows (b,s)
constexpr int cNQKV = cH * cD + 2 * cD; // 2304
constexpr float cEPS = 1.1920928955078125e-07f;

__device__ __forceinline__ unsigned short f2bf(float f) {
  union { float f; unsigned u; } v; v.f = f;
  unsigned r = v.u + 0x7fffu + ((v.u >> 16) & 1u);
  return (unsigned short)(r >> 16);
}

__device__ __forceinline__ f32x4 mfma16(bf16x8 a, bf16x8 b, f32x4 c) {
  return __builtin_amdgcn_mfma_f32_16x16x32_bf16(a, b, c, 0, 0, 0);
}

// ---------------- GEMM: C[M x N] = A[M x K] * W[N x K]^T ----------------
template <bool A_BF16>
__global__ __launch_bounds__(256) void gemm128(
    const void* __restrict__ Ap,
    const float* __restrict__ W0, const float* __restrict__ W1,
    const float* __restrict__ W2,
    float* __restrict__ C, int N, int K)
{
  __shared__ unsigned short Al[128][40];
  __shared__ unsigned short Bl[128][40];
  const int t = threadIdx.x;
  const int bm = blockIdx.x, bn = blockIdx.y;
  const int lane = t & 63, w = t >> 6;
  const int wr = w >> 1, wc = w & 1;
  const int lr = t >> 3;          // 0..31
  const int lc = (t & 7) << 2;    // 0,4,..,28

  const float* Wp; long wbase;
  if (bn < 16)       { Wp = W0; wbase = (long)bn * 128; }
  else if (bn == 16) { Wp = W1; wbase = 0; }
  else               { Wp = W2; wbase = 0; }

  f32x4 acc[4][4] = {};

  for (int k0 = 0; k0 < K; k0 += 32) {
    #pragma unroll
    for (int i = 0; i < 4; ++i) {
      int r = (i << 5) + lr;
      long ga = (long)(bm * 128 + r) * K + k0 + lc;
      if (A_BF16) {
        ushort4 v = *reinterpret_cast<const ushort4*>((const unsigned short*)Ap + ga);
        *reinterpret_cast<ushort4*>(&Al[r][lc]) = v;
      } else {
        float4 v = *reinterpret_cast<const float4*>((const float*)Ap + ga);
        ushort4 p; p.x = f2bf(v.x); p.y = f2bf(v.y); p.z = f2bf(v.z); p.w = f2bf(v.w);
        *reinterpret_cast<ushort4*>(&Al[r][lc]) = p;
      }
      long gb = (wbase + r) * (long)K + k0 + lc;
      float4 vb = *reinterpret_cast<const float4*>(Wp + gb);
      ushort4 pb; pb.x = f2bf(vb.x); pb.y = f2bf(vb.y); pb.z = f2bf(vb.z); pb.w = f2bf(vb.w);
      *reinterpret_cast<ushort4*>(&Bl[r][lc]) = pb;
    }
    __syncthreads();
    bf16x8 af[4], bff[4];
    #pragma unroll
    for (int m = 0; m < 4; ++m)
      af[m] = *reinterpret_cast<const bf16x8*>(&Al[wr * 64 + m * 16 + (lane & 15)][(lane >> 4) * 8]);
    #pragma unroll
    for (int n = 0; n < 4; ++n)
      bff[n] = *reinterpret_cast<const bf16x8*>(&Bl[wc * 64 + n * 16 + (lane & 15)][(lane >> 4) * 8]);
    #pragma unroll
    for (int m = 0; m < 4; ++m)
      #pragma unroll
      for (int n = 0; n < 4; ++n)
        acc[m][n] = mfma16(af[m], bff[n], acc[m][n]);
    __syncthreads();
  }

  #pragma unroll
  for (int m = 0; m < 4; ++m) {
    int row = bm * 128 + wr * 64 + m * 16 + (lane >> 4) * 4;
    #pragma unroll
    for (int n = 0; n < 4; ++n) {
      int col = bn * 128 + wc * 64 + n * 16 + (lane & 15);
      #pragma unroll
      for (int r = 0; r < 4; ++r)
        C[(long)(row + r) * N + col] = acc[m][n][r];
    }
  }
}

// ------------- RoPE + RMSNorm epilogue on qkv rows -------------
__global__ __launch_bounds__(256) void rope_norm(
    const float* __restrict__ C,      // [B*S][2304]
    const float* __restrict__ cosb,   // [S][64]
    const float* __restrict__ sinb,   // [S][64]
    unsigned short* __restrict__ Qn,  // [B][H][S][D] bf16
    unsigned short* __restrict__ Kn,  // [B][S][D]    bf16
    unsigned short* __restrict__ Vn)  // [B][S][D]    bf16
{
  const int row = blockIdx.x;              // b*S + s
  const int b = row >> 11, s = row & (cS - 1);
  const int w = threadIdx.x >> 6, lane = threadIdx.x & 63;
  const float cv = cosb[s * 64 + lane];
  const float sv = sinb[s * 64 + lane];
  const float* base = C + (long)row * cNQKV;

  #pragma unroll
  for (int i = 0; i < 4; ++i) {
    int h = w * 4 + i;
    float x1 = base[h * 128 + lane];
    float x2 = base[h * 128 + 64 + lane];
    float o1 = x1 * cv + x2 * sv;
    float o2 = x2 * cv - x1 * sv;
    float ss = o1 * o1 + o2 * o2;
    #pragma unroll
    for (int m = 1; m < 64; m <<= 1) ss += __shfl_xor(ss, m);
    float sc = rsqrtf(ss * (1.0f / 128.0f) + cEPS);
    long o = ((long)(b * cH + h) * cS + s) * cD + lane;
    Qn[o] = f2bf(o1 * sc);
    Qn[o + 64] = f2bf(o2 * sc);
  }
  if (w == 0) {
    float x1 = base[2048 + lane], x2 = base[2048 + 64 + lane];
    float o1 = x1 * cv + x2 * sv;
    float o2 = x2 * cv - x1 * sv;
    float ss = o1 * o1 + o2 * o2;
    #pragma unroll
    for (int m = 1; m < 64; m <<= 1) ss += __shfl_xor(ss, m);
    float sc = rsqrtf(ss * (1.0f / 128.0f) + cEPS);
    long o = ((long)b * cS + s) * cD + lane;
    Kn[o] = f2bf(o1 * sc);
    Kn[o + 64] = f2bf(o2 * sc);
  }
  if (w == 1) {
    long o = ((long)b * cS + s) * cD + lane;
    Vn[o] = f2bf(base[2176 + lane]);
    Vn[o + 64] = f2bf(base[2176 + 64 + lane]);
  }
}

// ------------- Flash attention v2 (causal, MQA) -------------
// Folded-triangle grid: block bx does q-tiles bx and 31-bx (uniform 33 kv-tiles).
// 4 waves x 16 q rows; KVBLK=64. Swapped QK^T (S^T = K*Q^T) -> lane-local
// softmax; in-register P repack to PV A-fragment via shfl_xor(16/32/48).
__global__ __launch_bounds__(256) void attn2(
    const unsigned short* __restrict__ Qn,
    const unsigned short* __restrict__ Kn,
    const unsigned short* __restrict__ Vn,
    unsigned short* __restrict__ O)    // [B*S][H*D] bf16
{
  __shared__ unsigned short Kl[64][136];   // 17408 B (aliased by Ol at epilogue)
  __shared__ unsigned short Vt[128][72];   // 18432 B, V transposed [d][kv]
  const int t = threadIdx.x, w = t >> 6, lane = t & 63;
  const int hi = lane >> 4, l15 = lane & 15;
  const int h = blockIdx.y, b = blockIdx.z;
  const unsigned short* Qb = Qn + (long)(b * cH + h) * cS * cD;
  const unsigned short* Kb = Kn + (long)b * cS * cD;
  const unsigned short* Vb = Vn + (long)b * cS * cD;

  const int sr = t >> 4;          // K stage row 0..15 (+16i)
  const int sc = (t & 15) << 3;   // K stage col (shorts)
  const int dv = t & 127, half = t >> 7;  // V stage map
  const float sc2 = 0.08838834764831845f * 1.442695040888963f;  // scale*log2(e)

  #pragma unroll 1
  for (int pass = 0; pass < 2; ++pass) {
    const int qt = (pass == 0) ? blockIdx.x : 31 - blockIdx.x;
    const int q0 = qt * 64;
    const int qrow = q0 + w * 16 + l15;   // this lane's q row (S^T column)

    bf16x8 qf[4];
    #pragma unroll
    for (int kc = 0; kc < 4; ++kc)
      qf[kc] = *reinterpret_cast<const bf16x8*>(&Qb[(long)qrow * cD + kc * 32 + hi * 8]);

    f32x4 oacc[8] = {};
    float mrun = -1e30f, lrun = 0.f;
    const int nt = qt + 1;

    #pragma unroll 1
    for (int kt = 0; kt < nt; ++kt) {
      const int kv0 = kt * 64;
      __syncthreads();
      // stage K [64][128] linear (padded 136)
      #pragma unroll
      for (int i = 0; i < 4; ++i) {
        int r = sr + 16 * i;
        uint4 kvec = *reinterpret_cast<const uint4*>(&Kb[(long)(kv0 + r) * cD + sc]);
        *reinterpret_cast<uint4*>(&Kl[r][sc]) = kvec;
      }
      // stage V transposed: Vt[d][kv]
      #pragma unroll
      for (int g = 0; g < 4; ++g) {
        int kvg = half * 4 + g;  // 0..7
        unsigned e[8];
        #pragma unroll
        for (int j = 0; j < 8; ++j)
          e[j] = Vb[(long)(kv0 + kvg * 8 + j) * cD + dv];
        uint4 pk;
        pk.x = e[0] | (e[1] << 16); pk.y = e[2] | (e[3] << 16);
        pk.z = e[4] | (e[5] << 16); pk.w = e[6] | (e[7] << 16);
        *reinterpret_cast<uint4*>(&Vt[dv][kvg * 8]) = pk;
      }
      __syncthreads();

      // QK^T swapped: st[n][r] = S^T[kv = n*16 + hi*4 + r][q]
      f32x4 st[4] = {};
      #pragma unroll
      for (int kc = 0; kc < 4; ++kc) {
        #pragma unroll
        for (int n = 0; n < 4; ++n) {
          bf16x8 kf = *reinterpret_cast<const bf16x8*>(&Kl[n * 16 + l15][kc * 32 + hi * 8]);
          st[n] = mfma16(kf, qf[kc], st[n]);
        }
      }

      // scale (+ mask on diagonal tile only), log2 domain
      float p[4][4];
      if (kt == qt) {
        #pragma unroll
        for (int n = 0; n < 4; ++n)
          #pragma unroll
          for (int r = 0; r < 4; ++r) {
            int kv = kv0 + n * 16 + hi * 4 + r;
            p[n][r] = (kv <= qrow) ? st[n][r] * sc2 : -1e30f;
          }
      } else {
        #pragma unroll
        for (int n = 0; n < 4; ++n)
          #pragma unroll
          for (int r = 0; r < 4; ++r)
            p[n][r] = st[n][r] * sc2;
      }

      // lane-local max over 16 + butterfly over hi-partners
      float pmax = p[0][0];
      #pragma unroll
      for (int n = 0; n < 4; ++n)
        #pragma unroll
        for (int r = 0; r < 4; ++r) pmax = fmaxf(pmax, p[n][r]);
      pmax = fmaxf(pmax, __shfl_xor(pmax, 16));
      pmax = fmaxf(pmax, __shfl_xor(pmax, 32));
      float mnew = fmaxf(mrun, pmax);
      float alpha = exp2f(mrun - mnew);
      mrun = mnew;

      float psum = 0.f;
      #pragma unroll
      for (int n = 0; n < 4; ++n)
        #pragma unroll
        for (int r = 0; r < 4; ++r) {
          p[n][r] = exp2f(p[n][r] - mnew);
          psum += p[n][r];
        }
      psum += __shfl_xor(psum, 16);
      psum += __shfl_xor(psum, 32);
      lrun = lrun * alpha + psum;

      #pragma unroll
      for (int n = 0; n < 8; ++n)
        #pragma unroll
        for (int r = 0; r < 4; ++r) oacc[n][r] *= alpha;

      // pack p -> bf16 pairs per n-chunk
      unsigned pkl[4], pkh[4];
      #pragma unroll
      for (int n = 0; n < 4; ++n) {
        pkl[n] = (unsigned)f2bf(p[n][0]) | ((unsigned)f2bf(p[n][1]) << 16);
        pkh[n] = (unsigned)f2bf(p[n][2]) | ((unsigned)f2bf(p[n][3]) << 16);
      }

      // repack to PV A-fragment: pa[c][j] = P[q][c*32 + hi*8 + j]
      bf16x8 pa[2];
      #pragma unroll
      for (int c = 0; c < 2; ++c) {
        int ns = 2 * c + (hi >> 1);
        int no = 2 * c + ((hi >> 1) ^ 1);
        unsigned own0 = pkl[ns], own1 = pkh[ns];
        unsigned ot0 = pkl[no], ot1 = pkh[no];
        unsigned a160 = __shfl_xor(own0, 16), a161 = __shfl_xor(own1, 16);
        unsigned a320 = __shfl_xor(ot0, 32),  a321 = __shfl_xor(ot1, 32);
        unsigned a480 = __shfl_xor(ot0, 48),  a481 = __shfl_xor(ot1, 48);
        unsigned w0 = hi == 0 ? own0 : hi == 1 ? a480 : hi == 2 ? a320 : a160;
        unsigned w1 = hi == 0 ? own1 : hi == 1 ? a481 : hi == 2 ? a321 : a161;
        unsigned w2 = hi == 0 ? a160 : hi == 1 ? a320 : hi == 2 ? a480 : own0;
        unsigned w3 = hi == 0 ? a161 : hi == 1 ? a321 : hi == 2 ? a481 : own1;
        union { unsigned u[4]; bf16x8 v; } cvt;
        cvt.u[0] = w0; cvt.u[1] = w1; cvt.u[2] = w2; cvt.u[3] = w3;
        pa[c] = cvt.v;
      }

      // PV swapped: oacc[n2][r] = O^T[d = n2*16 + hi*4 + r][q]
      #pragma unroll
      for (int n2 = 0; n2 < 8; ++n2) {
        #pragma unroll
        for (int c = 0; c < 2; ++c) {
          bf16x8 vf = *reinterpret_cast<const bf16x8*>(&Vt[n2 * 16 + l15][c * 32 + hi * 8]);
          oacc[n2] = mfma16(vf, pa[c], oacc[n2]);
        }
      }
    }

    // epilogue: transpose O^T -> O via per-wave LDS (aliases Kl), coalesced store
    __syncthreads();   // all waves done reading Kl/Vt
    {
      float inv = 1.0f / lrun;
      unsigned short (*Ol)[136] = reinterpret_cast<unsigned short(*)[136]>(&Kl[w * 16][0]);
      #pragma unroll
      for (int n2 = 0; n2 < 8; ++n2)
        #pragma unroll
        for (int r = 0; r < 4; ++r)
          Ol[l15][n2 * 16 + hi * 4 + r] = f2bf(oacc[n2][r] * inv);
      __syncthreads();
      #pragma unroll
      for (int i = 0; i < 4; ++i) {
        int row = hi + 4 * i;
        uint4 ov = *reinterpret_cast<const uint4*>(&Ol[row][l15 * 8]);
        *reinterpret_cast<uint4*>(
            &O[(long)(b * cS + q0 + w * 16 + row) * (cH * cD) + h * cD + l15 * 8]) = ov;
      }
    }
  }
}

extern "C" void kernel_launch(void* const* d_in, const int* in_sizes, int n_in,
                              void* d_out, int out_size, void* d_ws, size_t ws_size,
                              hipStream_t stream) {
  const float* x    = (const float*)d_in[0];
  const float* cosb = (const float*)d_in[1];
  const float* sinb = (const float*)d_in[2];
  const float* wq   = (const float*)d_in[3];
  const float* wk   = (const float*)d_in[4];
  const float* wv   = (const float*)d_in[5];
  const float* wo   = (const float*)d_in[6];
  float* out = (float*)d_out;

  char* ws = (char*)d_ws;
  float* Cqkv        = (float*)ws;                                   // 37,748,736 B
  unsigned short* Qn = (unsigned short*)(ws + 37748736);             // 16,777,216 B
  unsigned short* Kn = (unsigned short*)(ws + 37748736 + 16777216);  //  1,048,576 B
  unsigned short* Vn = (unsigned short*)(ws + 37748736 + 16777216 + 1048576);
  unsigned short* Ob = (unsigned short*)ws;  // aliases Cqkv (dead after rope_norm)

  gemm128<false><<<dim3(32, 18), 256, 0, stream>>>(x, wq, wk, wv, Cqkv, cNQKV, cHID);
  rope_norm<<<dim3(cM), 256, 0, stream>>>(Cqkv, cosb, sinb, Qn, Kn, Vn);
  attn2<<<dim3(16, 16, 2), 256, 0, stream>>>(Qn, Kn, Vn, Ob);
  gemm128<true><<<dim3(32, 16), 256, 0, stream>>>(Ob, wo, wo, wo, out, 2048, cHID);
}

// Round 4
// 244.033 us; speedup vs baseline: 1.7382x; 1.1606x over previous
//
#include <hip/hip_runtime.h>
#include <hip/hip_bf16.h>

typedef __attribute__((ext_vector_type(8))) short bf16x8;
typedef __attribute__((ext_vector_type(4))) float f32x4;

constexpr int cH = 16, cD = 128, cHID = 2048, cS = 2048, cB = 2;
constexpr float cEPS = 1.1920928955078125e-07f;

__device__ __forceinline__ unsigned short f2bf(float f) {
  union { float f; unsigned u; } v; v.f = f;
  unsigned r = v.u + 0x7fffu + ((v.u >> 16) & 1u);
  return (unsigned short)(r >> 16);
}
__device__ __forceinline__ float bf2f(unsigned short h) {
  union { unsigned u; float f; } v; v.u = ((unsigned)h) << 16; return v.f;
}
__device__ __forceinline__ unsigned pk2(float a, float b) {
  return (unsigned)f2bf(a) | ((unsigned)f2bf(b) << 16);
}
__device__ __forceinline__ f32x4 mfma16(bf16x8 a, bf16x8 b, f32x4 c) {
  return __builtin_amdgcn_mfma_f32_16x16x32_bf16(a, b, c, 0, 0, 0);
}
// async global->LDS, 16B per lane; lds ptr must be wave-uniform base.
__device__ __forceinline__ void gl2l(const void* g, void* l) {
  __builtin_amdgcn_global_load_lds(
      (const __attribute__((address_space(1))) unsigned int*)g,
      (__attribute__((address_space(3))) unsigned int*)l, 16, 0, 0);
}

// -------- cvt fp32 -> bf16 (x, wq, wk, wv concatenated ranges) --------
__global__ __launch_bounds__(256) void cvt_qkv(
    const float* __restrict__ x, const float* __restrict__ wq,
    const float* __restrict__ wk, const float* __restrict__ wv,
    unsigned short* __restrict__ xb, unsigned short* __restrict__ wqb,
    unsigned short* __restrict__ wkb, unsigned short* __restrict__ wvb)
{
  long i = (long)blockIdx.x * 2048 + threadIdx.x * 8;
  const float* s; unsigned short* d; long off;
  if (i < 8388608)       { s = x;  d = xb;  off = i; }
  else if (i < 12582912) { s = wq; d = wqb; off = i - 8388608; }
  else if (i < 12845056) { s = wk; d = wkb; off = i - 12582912; }
  else                   { s = wv; d = wvb; off = i - 12845056; }
  float4 v0 = *reinterpret_cast<const float4*>(s + off);
  float4 v1 = *reinterpret_cast<const float4*>(s + off + 4);
  uint4 o; o.x = pk2(v0.x, v0.y); o.y = pk2(v0.z, v0.w);
  o.z = pk2(v1.x, v1.y); o.w = pk2(v1.z, v1.w);
  *reinterpret_cast<uint4*>(d + off) = o;
}

__global__ __launch_bounds__(256) void cvt_wo(
    const float* __restrict__ wo, unsigned short* __restrict__ wob)
{
  long i = (long)blockIdx.x * 2048 + threadIdx.x * 8;
  float4 v0 = *reinterpret_cast<const float4*>(wo + i);
  float4 v1 = *reinterpret_cast<const float4*>(wo + i + 4);
  uint4 o; o.x = pk2(v0.x, v0.y); o.y = pk2(v0.z, v0.w);
  o.z = pk2(v1.x, v1.y); o.w = pk2(v1.z, v1.w);
  *reinterpret_cast<uint4*>(wob + i) = o;
}

// -------- QKV GEMM (m97 structure) + fused RoPE/RMSNorm epilogue --------
// grid (32, 18). bn<16: Q head bn; bn==16: K (written d-swizzled); bn==17: V.
__global__ __launch_bounds__(256) void gemm_qkv(
    const unsigned short* __restrict__ A,    // xb [4096][2048]
    const unsigned short* __restrict__ Wq,   // [2048][2048]
    const unsigned short* __restrict__ Wk,   // [128][2048]
    const unsigned short* __restrict__ Wv,   // [128][2048]
    const float* __restrict__ cosb, const float* __restrict__ sinb,
    unsigned short* __restrict__ Qn,         // [B][H][S][D]
    unsigned short* __restrict__ Kn,         // [B][S][D] swizzled
    unsigned short* __restrict__ Vn)         // [B][S][D]
{
  __shared__ unsigned short lds[17408];      // staging 8192 us; epilogue Ct[128][136]
  const int t = threadIdx.x;
  const int bm = blockIdx.x, bn = blockIdx.y;
  const int lane = t & 63, w = t >> 6;
  const int wr = w >> 1, wc = w & 1, hi = lane >> 4, l15 = lane & 15;

  const unsigned short* Wp; long wbase;
  if (bn < 16)       { Wp = Wq; wbase = (long)bn * 128; }
  else if (bn == 16) { Wp = Wk; wbase = 0; }
  else               { Wp = Wv; wbase = 0; }

  f32x4 acc[4][4] = {};

  for (int k0 = 0; k0 < 2048; k0 += 32) {
    #pragma unroll
    for (int i = 0; i < 2; ++i) {
      int c = w + 4 * i;
      gl2l(A + (long)(bm * 128 + 16 * c + (lane >> 2)) * 2048 + k0 + (lane & 3) * 8,
           &lds[c * 512]);
      gl2l(Wp + (wbase + 16 * c + (lane >> 2)) * 2048 + k0 + (lane & 3) * 8,
           &lds[4096 + c * 512]);
    }
    __syncthreads();
    bf16x8 af[4], bff[4];
    #pragma unroll
    for (int m = 0; m < 4; ++m)
      af[m] = *reinterpret_cast<const bf16x8*>(&lds[(wr * 64 + m * 16 + l15) * 32 + hi * 8]);
    #pragma unroll
    for (int n = 0; n < 4; ++n)
      bff[n] = *reinterpret_cast<const bf16x8*>(&lds[4096 + (wc * 64 + n * 16 + l15) * 32 + hi * 8]);
    #pragma unroll
    for (int m = 0; m < 4; ++m)
      #pragma unroll
      for (int n = 0; n < 4; ++n)
        acc[m][n] = mfma16(af[m], bff[n], acc[m][n]);
    __syncthreads();
  }

  // ---- epilogue: acc -> bf16 Ct, then rope/norm per row ----
  #pragma unroll
  for (int m = 0; m < 4; ++m)
    #pragma unroll
    for (int n = 0; n < 4; ++n)
      #pragma unroll
      for (int r = 0; r < 4; ++r)
        lds[(wr * 64 + m * 16 + hi * 4 + r) * 136 + wc * 64 + n * 16 + l15] =
            f2bf(acc[m][n][r]);
  __syncthreads();

  const int r = t >> 1, h2 = t & 1;
  const int grow = bm * 128 + r, b = grow >> 11, s = grow & 2047;
  const unsigned short* Crow = &lds[r * 136];

  if (bn == 17) {
    long base = ((long)b * cS + s) * cD + h2 * 64;
    #pragma unroll
    for (int g = 0; g < 8; ++g) {
      const unsigned short* p = Crow + h2 * 64 + g * 8;
      uint4 o;
      o.x = (unsigned)p[0] | ((unsigned)p[1] << 16);
      o.y = (unsigned)p[2] | ((unsigned)p[3] << 16);
      o.z = (unsigned)p[4] | ((unsigned)p[5] << 16);
      o.w = (unsigned)p[6] | ((unsigned)p[7] << 16);
      *reinterpret_cast<uint4*>(&Vn[base + g * 8]) = o;
    }
  } else {
    float o1[32], o2[32];
    const float* cp = cosb + (long)s * 64 + h2 * 32;
    const float* sp = sinb + (long)s * 64 + h2 * 32;
    float ss = 0.f;
    #pragma unroll
    for (int j = 0; j < 32; ++j) {
      float x1 = bf2f(Crow[h2 * 32 + j]);
      float x2 = bf2f(Crow[64 + h2 * 32 + j]);
      float cv = cp[j], sv = sp[j];
      o1[j] = x1 * cv + x2 * sv;
      o2[j] = x2 * cv - x1 * sv;
      ss += o1[j] * o1[j] + o2[j] * o2[j];
    }
    ss += __shfl_xor(ss, 1);
    float scn = rsqrtf(ss * (1.0f / 128.0f) + cEPS);
    if (bn < 16) {
      long base = (((long)b * cH + bn) * cS + s) * cD + h2 * 32;
      #pragma unroll
      for (int g = 0; g < 4; ++g) {
        uint4 o;
        o.x = pk2(o1[g*8+0]*scn, o1[g*8+1]*scn); o.y = pk2(o1[g*8+2]*scn, o1[g*8+3]*scn);
        o.z = pk2(o1[g*8+4]*scn, o1[g*8+5]*scn); o.w = pk2(o1[g*8+6]*scn, o1[g*8+7]*scn);
        *reinterpret_cast<uint4*>(&Qn[base + g * 8]) = o;
      }
      #pragma unroll
      for (int g = 0; g < 4; ++g) {
        uint4 o;
        o.x = pk2(o2[g*8+0]*scn, o2[g*8+1]*scn); o.y = pk2(o2[g*8+2]*scn, o2[g*8+3]*scn);
        o.z = pk2(o2[g*8+4]*scn, o2[g*8+5]*scn); o.w = pk2(o2[g*8+6]*scn, o2[g*8+7]*scn);
        *reinterpret_cast<uint4*>(&Qn[base + 64 + g * 8]) = o;
      }
    } else {
      long base = ((long)b * cS + s) * cD;
      int xs = (s & 7) << 3;
      #pragma unroll
      for (int g = 0; g < 4; ++g) {
        int dlo = h2 * 32 + g * 8;
        uint4 o;
        o.x = pk2(o1[g*8+0]*scn, o1[g*8+1]*scn); o.y = pk2(o1[g*8+2]*scn, o1[g*8+3]*scn);
        o.z = pk2(o1[g*8+4]*scn, o1[g*8+5]*scn); o.w = pk2(o1[g*8+6]*scn, o1[g*8+7]*scn);
        *reinterpret_cast<uint4*>(&Kn[base + (dlo ^ xs)]) = o;
        uint4 p;
        p.x = pk2(o2[g*8+0]*scn, o2[g*8+1]*scn); p.y = pk2(o2[g*8+2]*scn, o2[g*8+3]*scn);
        p.z = pk2(o2[g*8+4]*scn, o2[g*8+5]*scn); p.w = pk2(o2[g*8+6]*scn, o2[g*8+7]*scn);
        *reinterpret_cast<uint4*>(&Kn[base + 64 + (dlo ^ xs)]) = p;
      }
    }
  }
}

// -------- V transpose: Vn[b][s][d] -> Vt[b][d][s ^ ((d&7)<<3)] --------
__global__ __launch_bounds__(256) void vtrans(
    const unsigned short* __restrict__ Vn, unsigned short* __restrict__ Vt)
{
  __shared__ unsigned short Tl[64][72];
  const int t = threadIdx.x;
  const int st = blockIdx.x * 64, dt = blockIdx.y * 64, b = blockIdx.z;
  const unsigned short* Vb = Vn + (long)b * cS * cD;
  #pragma unroll
  for (int i = 0; i < 2; ++i) {
    int r = i * 32 + (t >> 3), c8 = (t & 7) * 8;
    *reinterpret_cast<uint4*>(&Tl[r][c8]) =
        *reinterpret_cast<const uint4*>(&Vb[(long)(st + r) * cD + dt + c8]);
  }
  __syncthreads();
  unsigned short* Vo = Vt + (long)b * cD * cS;
  #pragma unroll
  for (int i = 0; i < 2; ++i) {
    int d = i * 32 + (t >> 3), sb = (t & 7) * 8;
    unsigned short e[8];
    #pragma unroll
    for (int j = 0; j < 8; ++j) e[j] = Tl[sb + j][d];
    uint4 o;
    o.x = (unsigned)e[0] | ((unsigned)e[1] << 16);
    o.y = (unsigned)e[2] | ((unsigned)e[3] << 16);
    o.z = (unsigned)e[4] | ((unsigned)e[5] << 16);
    o.w = (unsigned)e[6] | ((unsigned)e[7] << 16);
    int dg = dt + d;
    *reinterpret_cast<uint4*>(&Vo[(long)dg * cS + st + (sb ^ ((dg & 7) << 3))]) = o;
  }
}

// -------- Flash attention (causal MQA), global_load_lds staging --------
__global__ __launch_bounds__(256) void attn2(
    const unsigned short* __restrict__ Qn,
    const unsigned short* __restrict__ Kn,   // swizzled
    const unsigned short* __restrict__ Vt,   // [b][d][s] swizzled
    unsigned short* __restrict__ O)          // [B*S][H*D] bf16
{
  __shared__ unsigned short lds[16384];      // Kl[64][128] | Vl[128][64]
  const int t = threadIdx.x, w = t >> 6, lane = t & 63;
  const int hi = lane >> 4, l15 = lane & 15;
  const int h = blockIdx.y, b = blockIdx.z;
  const unsigned short* Qb = Qn + (long)(b * cH + h) * cS * cD;
  const unsigned short* Kb = Kn + (long)b * cS * cD;
  const unsigned short* Vtb = Vt + (long)b * cD * cS;
  const int x3 = (l15 & 7) << 3;             // frag-read XOR (us units)
  const float sc2 = 0.08838834764831845f * 1.442695040888963f;

  #pragma unroll 1
  for (int pass = 0; pass < 2; ++pass) {
    const int qt = (pass == 0) ? blockIdx.x : 31 - blockIdx.x;
    const int q0 = qt * 64;
    const int qrow = q0 + w * 16 + l15;

    bf16x8 qf[4];
    #pragma unroll
    for (int kc = 0; kc < 4; ++kc)
      qf[kc] = *reinterpret_cast<const bf16x8*>(&Qb[(long)qrow * cD + kc * 32 + hi * 8]);

    f32x4 oacc[8] = {};
    float mrun = -1e30f, lrun = 0.f;
    const int nt = qt + 1;

    #pragma unroll 1
    for (int kt = 0; kt < nt; ++kt) {
      const int kv0 = kt * 64;
      __syncthreads();
      #pragma unroll
      for (int i = 0; i < 4; ++i) {
        int c = 4 * w + i;
        gl2l(Kb + (long)(kv0 + 4 * c + (lane >> 4)) * cD + (lane & 15) * 8,
             &lds[c * 512]);
        gl2l(Vtb + (long)(8 * c + (lane >> 3)) * cS + kv0 + (lane & 7) * 8,
             &lds[8192 + c * 512]);
      }
      __syncthreads();

      // QK^T swapped: st[n][r] = S^T[kv = n*16 + hi*4 + r][q]
      f32x4 st[4] = {};
      #pragma unroll
      for (int kc = 0; kc < 4; ++kc) {
        #pragma unroll
        for (int n = 0; n < 4; ++n) {
          bf16x8 kf = *reinterpret_cast<const bf16x8*>(
              &lds[(n * 16 + l15) * 128 + ((kc * 32 + hi * 8) ^ x3)]);
          st[n] = mfma16(kf, qf[kc], st[n]);
        }
      }

      // scale (+ causal mask on the diagonal tile only), log2 domain
      float p[4][4];
      if (kt == qt) {
        #pragma unroll
        for (int n = 0; n < 4; ++n)
          #pragma unroll
          for (int r = 0; r < 4; ++r) {
            int kv = kv0 + n * 16 + hi * 4 + r;
            p[n][r] = (kv <= qrow) ? st[n][r] * sc2 : -1e30f;
          }
      } else {
        #pragma unroll
        for (int n = 0; n < 4; ++n)
          #pragma unroll
          for (int r = 0; r < 4; ++r)
            p[n][r] = st[n][r] * sc2;
      }

      float pmax = p[0][0];
      #pragma unroll
      for (int n = 0; n < 4; ++n)
        #pragma unroll
        for (int r = 0; r < 4; ++r) pmax = fmaxf(pmax, p[n][r]);
      pmax = fmaxf(pmax, __shfl_xor(pmax, 16));
      pmax = fmaxf(pmax, __shfl_xor(pmax, 32));
      float mnew = fmaxf(mrun, pmax);
      float alpha = exp2f(mrun - mnew);
      mrun = mnew;

      float psum = 0.f;
      #pragma unroll
      for (int n = 0; n < 4; ++n)
        #pragma unroll
        for (int r = 0; r < 4; ++r) {
          p[n][r] = exp2f(p[n][r] - mnew);
          psum += p[n][r];
        }
      psum += __shfl_xor(psum, 16);
      psum += __shfl_xor(psum, 32);
      lrun = lrun * alpha + psum;

      #pragma unroll
      for (int n = 0; n < 8; ++n)
        #pragma unroll
        for (int r = 0; r < 4; ++r) oacc[n][r] *= alpha;

      unsigned pkl[4], pkh[4];
      #pragma unroll
      for (int n = 0; n < 4; ++n) {
        pkl[n] = pk2(p[n][0], p[n][1]);
        pkh[n] = pk2(p[n][2], p[n][3]);
      }

      // repack to PV A-fragment: pa[c][j] = P[q][c*32 + hi*8 + j]
      bf16x8 pa[2];
      #pragma unroll
      for (int c = 0; c < 2; ++c) {
        int ns = 2 * c + (hi >> 1);
        int no = 2 * c + ((hi >> 1) ^ 1);
        unsigned own0 = pkl[ns], own1 = pkh[ns];
        unsigned ot0 = pkl[no], ot1 = pkh[no];
        unsigned a160 = __shfl_xor(own0, 16), a161 = __shfl_xor(own1, 16);
        unsigned a320 = __shfl_xor(ot0, 32),  a321 = __shfl_xor(ot1, 32);
        unsigned a480 = __shfl_xor(ot0, 48),  a481 = __shfl_xor(ot1, 48);
        unsigned w0 = hi == 0 ? own0 : hi == 1 ? a480 : hi == 2 ? a320 : a160;
        unsigned w1 = hi == 0 ? own1 : hi == 1 ? a481 : hi == 2 ? a321 : a161;
        unsigned w2 = hi == 0 ? a160 : hi == 1 ? a320 : hi == 2 ? a480 : own0;
        unsigned w3 = hi == 0 ? a161 : hi == 1 ? a321 : hi == 2 ? a481 : own1;
        union { unsigned u[4]; bf16x8 v; } cvt;
        cvt.u[0] = w0; cvt.u[1] = w1; cvt.u[2] = w2; cvt.u[3] = w3;
        pa[c] = cvt.v;
      }

      // PV swapped: oacc[n2][r] = O^T[d = n2*16 + hi*4 + r][q]
      #pragma unroll
      for (int n2 = 0; n2 < 8; ++n2) {
        #pragma unroll
        for (int c = 0; c < 2; ++c) {
          bf16x8 vf = *reinterpret_cast<const bf16x8*>(
              &lds[8192 + (n2 * 16 + l15) * 64 + ((c * 32 + hi * 8) ^ x3)]);
          oacc[n2] = mfma16(vf, pa[c], oacc[n2]);
        }
      }
    }

    // epilogue: O^T -> O via per-wave LDS transpose, coalesced store
    __syncthreads();
    {
      float inv = 1.0f / lrun;
      unsigned short* Ol = &lds[w * 2176];   // [16][136]
      #pragma unroll
      for (int n2 = 0; n2 < 8; ++n2)
        #pragma unroll
        for (int r = 0; r < 4; ++r)
          Ol[l15 * 136 + n2 * 16 + hi * 4 + r] = f2bf(oacc[n2][r] * inv);
      __syncthreads();
      #pragma unroll
      for (int i = 0; i < 4; ++i) {
        int row = hi + 4 * i;
        uint4 ov = *reinterpret_cast<const uint4*>(&Ol[row * 136 + l15 * 8]);
        *reinterpret_cast<uint4*>(
            &O[(long)(b * cS + q0 + w * 16 + row) * (cH * cD) + h * cD + l15 * 8]) = ov;
      }
    }
  }
}

// -------- output GEMM (m97 structure), fp32 C --------
__global__ __launch_bounds__(256) void gemm_out(
    const unsigned short* __restrict__ A,    // Ob [4096][2048]
    const unsigned short* __restrict__ W,    // wob [2048][2048]
    float* __restrict__ C)
{
  __shared__ unsigned short lds[8192];
  const int t = threadIdx.x;
  const int bm = blockIdx.x, bn = blockIdx.y;
  const int lane = t & 63, w = t >> 6;
  const int wr = w >> 1, wc = w & 1, hi = lane >> 4, l15 = lane & 15;
  const long wbase = (long)bn * 128;

  f32x4 acc[4][4] = {};
  for (int k0 = 0; k0 < 2048; k0 += 32) {
    #pragma unroll
    for (int i = 0; i < 2; ++i) {
      int c = w + 4 * i;
      gl2l(A + (long)(bm * 128 + 16 * c + (lane >> 2)) * 2048 + k0 + (lane & 3) * 8,
           &lds[c * 512]);
      gl2l(W + (wbase + 16 * c + (lane >> 2)) * 2048 + k0 + (lane & 3) * 8,
           &lds[4096 + c * 512]);
    }
    __syncthreads();
    bf16x8 af[4], bff[4];
    #pragma unroll
    for (int m = 0; m < 4; ++m)
      af[m] = *reinterpret_cast<const bf16x8*>(&lds[(wr * 64 + m * 16 + l15) * 32 + hi * 8]);
    #pragma unroll
    for (int n = 0; n < 4; ++n)
      bff[n] = *reinterpret_cast<const bf16x8*>(&lds[4096 + (wc * 64 + n * 16 + l15) * 32 + hi * 8]);
    #pragma unroll
    for (int m = 0; m < 4; ++m)
      #pragma unroll
      for (int n = 0; n < 4; ++n)
        acc[m][n] = mfma16(af[m], bff[n], acc[m][n]);
    __syncthreads();
  }

  #pragma unroll
  for (int m = 0; m < 4; ++m) {
    int row = bm * 128 + wr * 64 + m * 16 + hi * 4;
    #pragma unroll
    for (int n = 0; n < 4; ++n) {
      int col = bn * 128 + wc * 64 + n * 16 + l15;
      #pragma unroll
      for (int r = 0; r < 4; ++r)
        C[(long)(row + r) * 2048 + col] = acc[m][n][r];
    }
  }
}

extern "C" void kernel_launch(void* const* d_in, const int* in_sizes, int n_in,
                              void* d_out, int out_size, void* d_ws, size_t ws_size,
                              hipStream_t stream) {
  const float* x    = (const float*)d_in[0];
  const float* cosb = (const float*)d_in[1];
  const float* sinb = (const float*)d_in[2];
  const float* wq   = (const float*)d_in[3];
  const float* wk   = (const float*)d_in[4];
  const float* wv   = (const float*)d_in[5];
  const float* wo   = (const float*)d_in[6];
  float* out = (float*)d_out;

  char* ws = (char*)d_ws;
  unsigned short* xb  = (unsigned short*)(ws);                 // 16,777,216 B
  unsigned short* wqb = (unsigned short*)(ws + 16777216);      //  8,388,608 B
  unsigned short* wkb = (unsigned short*)(ws + 25165824);      //    524,288 B
  unsigned short* wvb = (unsigned short*)(ws + 25690112);      //    524,288 B
  unsigned short* Qn  = (unsigned short*)(ws + 26214400);      // 16,777,216 B
  unsigned short* Kn  = (unsigned short*)(ws + 42991616);      //  1,048,576 B
  unsigned short* Vn  = (unsigned short*)(ws + 44040192);      //  1,048,576 B
  unsigned short* Vtg = (unsigned short*)(ws + 45088768);      //  1,048,576 B
  unsigned short* Ob  = (unsigned short*)ws;                   // alias xb (dead)
  unsigned short* wob = (unsigned short*)(ws + 16777216);      // alias wqb (dead)

  cvt_qkv<<<dim3(6400), 256, 0, stream>>>(x, wq, wk, wv, xb, wqb, wkb, wvb);
  gemm_qkv<<<dim3(32, 18), 256, 0, stream>>>(xb, wqb, wkb, wvb, cosb, sinb, Qn, Kn, Vn);
  vtrans<<<dim3(32, 2, 2), 256, 0, stream>>>(Vn, Vtg);
  cvt_wo<<<dim3(2048), 256, 0, stream>>>(wo, wob);
  attn2<<<dim3(16, 16, 2), 256, 0, stream>>>(Qn, Kn, Vtg, Ob);
  gemm_out<<<dim3(32, 16), 256, 0, stream>>>(Ob, wob, out);
}

// Round 5
// 214.085 us; speedup vs baseline: 1.9813x; 1.1399x over previous
//
#include <hip/hip_runtime.h>
#include <hip/hip_bf16.h>

typedef __attribute__((ext_vector_type(8))) short bf16x8;
typedef __attribute__((ext_vector_type(4))) float f32x4;

constexpr int cH = 16, cD = 128, cHID = 2048, cS = 2048, cB = 2;
constexpr float cEPS = 1.1920928955078125e-07f;

__device__ __forceinline__ unsigned short f2bf(float f) {
  union { float f; unsigned u; } v; v.f = f;
  unsigned r = v.u + 0x7fffu + ((v.u >> 16) & 1u);
  return (unsigned short)(r >> 16);
}
__device__ __forceinline__ float bf2f(unsigned short h) {
  union { unsigned u; float f; } v; v.u = ((unsigned)h) << 16; return v.f;
}
__device__ __forceinline__ unsigned pk2(float a, float b) {
  return (unsigned)f2bf(a) | ((unsigned)f2bf(b) << 16);
}
__device__ __forceinline__ f32x4 mfma16(bf16x8 a, bf16x8 b, f32x4 c) {
  return __builtin_amdgcn_mfma_f32_16x16x32_bf16(a, b, c, 0, 0, 0);
}
// async global->LDS, 16B per lane; lds ptr must be wave-uniform base.
__device__ __forceinline__ void gl2l(const void* g, void* l) {
  __builtin_amdgcn_global_load_lds(
      (const __attribute__((address_space(1))) unsigned int*)g,
      (__attribute__((address_space(3))) unsigned int*)l, 16, 0, 0);
}

// -------- cvt fp32 -> bf16 (x, wq, wk, wv concatenated ranges) --------
__global__ __launch_bounds__(256) void cvt_qkv(
    const float* __restrict__ x, const float* __restrict__ wq,
    const float* __restrict__ wk, const float* __restrict__ wv,
    unsigned short* __restrict__ xb, unsigned short* __restrict__ wqb,
    unsigned short* __restrict__ wkb, unsigned short* __restrict__ wvb)
{
  long i = (long)blockIdx.x * 2048 + threadIdx.x * 8;
  const float* s; unsigned short* d; long off;
  if (i < 8388608)       { s = x;  d = xb;  off = i; }
  else if (i < 12582912) { s = wq; d = wqb; off = i - 8388608; }
  else if (i < 12845056) { s = wk; d = wkb; off = i - 12582912; }
  else                   { s = wv; d = wvb; off = i - 12845056; }
  float4 v0 = *reinterpret_cast<const float4*>(s + off);
  float4 v1 = *reinterpret_cast<const float4*>(s + off + 4);
  uint4 o; o.x = pk2(v0.x, v0.y); o.y = pk2(v0.z, v0.w);
  o.z = pk2(v1.x, v1.y); o.w = pk2(v1.z, v1.w);
  *reinterpret_cast<uint4*>(d + off) = o;
}

__global__ __launch_bounds__(256) void cvt_wo(
    const float* __restrict__ wo, unsigned short* __restrict__ wob)
{
  long i = (long)blockIdx.x * 2048 + threadIdx.x * 8;
  float4 v0 = *reinterpret_cast<const float4*>(wo + i);
  float4 v1 = *reinterpret_cast<const float4*>(wo + i + 4);
  uint4 o; o.x = pk2(v0.x, v0.y); o.y = pk2(v0.z, v0.w);
  o.z = pk2(v1.x, v1.y); o.w = pk2(v1.z, v1.w);
  *reinterpret_cast<uint4*>(wob + i) = o;
}

// -------- QKV GEMM (m97 structure) + register RoPE/RMSNorm epilogue --------
// grid (32, 18). bn<16: Q head bn; bn==16: K (written d-swizzled); bn==17: V.
// Wave w owns rows [w*32, w*32+32) x all 128 cols: acc[2][8].
// RoPE pair (d, d+64) = n-frag n and n+4, same lane -> register-local.
__global__ __launch_bounds__(256) void gemm_qkv(
    const unsigned short* __restrict__ A,    // xb [4096][2048]
    const unsigned short* __restrict__ Wq,   // [2048][2048]
    const unsigned short* __restrict__ Wk,   // [128][2048]
    const unsigned short* __restrict__ Wv,   // [128][2048]
    const float* __restrict__ cosb, const float* __restrict__ sinb,
    unsigned short* __restrict__ Qn,         // [B][H][S][D]
    unsigned short* __restrict__ Kn,         // [B][S][D] swizzled
    unsigned short* __restrict__ Vn)         // [B][S][D]
{
  __shared__ unsigned short lds[8192];       // A[128][32] | B[128][32], 16 KB
  const int t = threadIdx.x;
  const int bm = blockIdx.x, bn = blockIdx.y;
  const int lane = t & 63, w = t >> 6;
  const int hi = lane >> 4, l15 = lane & 15;

  const unsigned short* Wp; long wbase;
  if (bn < 16)       { Wp = Wq; wbase = (long)bn * 128; }
  else if (bn == 16) { Wp = Wk; wbase = 0; }
  else               { Wp = Wv; wbase = 0; }

  f32x4 acc[2][8] = {};

  for (int k0 = 0; k0 < 2048; k0 += 32) {
    #pragma unroll
    for (int i = 0; i < 2; ++i) {
      int c = w + 4 * i;
      gl2l(A + (long)(bm * 128 + 16 * c + (lane >> 2)) * 2048 + k0 + (lane & 3) * 8,
           &lds[c * 512]);
      gl2l(Wp + (wbase + 16 * c + (lane >> 2)) * 2048 + k0 + (lane & 3) * 8,
           &lds[4096 + c * 512]);
    }
    __syncthreads();
    bf16x8 af[2], bff[8];
    #pragma unroll
    for (int m = 0; m < 2; ++m)
      af[m] = *reinterpret_cast<const bf16x8*>(&lds[(w * 32 + m * 16 + l15) * 32 + hi * 8]);
    #pragma unroll
    for (int n = 0; n < 8; ++n)
      bff[n] = *reinterpret_cast<const bf16x8*>(&lds[4096 + (n * 16 + l15) * 32 + hi * 8]);
    #pragma unroll
    for (int m = 0; m < 2; ++m)
      #pragma unroll
      for (int n = 0; n < 8; ++n)
        acc[m][n] = mfma16(af[m], bff[n], acc[m][n]);
    __syncthreads();
  }

  // ---- register epilogue: rope+rms (Q,K) or passthrough (V) ----
  const int rowbase = bm * 128 + w * 32;
  if (bn == 17) {
    #pragma unroll
    for (int m = 0; m < 2; ++m)
      #pragma unroll
      for (int r = 0; r < 4; ++r) {
        int grow = rowbase + m * 16 + hi * 4 + r;
        int b = grow >> 11, s = grow & 2047;
        long base = ((long)b * cS + s) * cD;
        #pragma unroll
        for (int n = 0; n < 8; ++n)
          Vn[base + n * 16 + l15] = f2bf(acc[m][n][r]);
      }
  } else {
    #pragma unroll
    for (int m = 0; m < 2; ++m)
      #pragma unroll
      for (int r = 0; r < 4; ++r) {
        int grow = rowbase + m * 16 + hi * 4 + r;
        int b = grow >> 11, s = grow & 2047;
        float o1[4], o2[4], ss = 0.f;
        #pragma unroll
        for (int n = 0; n < 4; ++n) {
          float cv = cosb[(long)s * 64 + n * 16 + l15];
          float sv = sinb[(long)s * 64 + n * 16 + l15];
          float x1 = acc[m][n][r], x2 = acc[m][n + 4][r];
          o1[n] = x1 * cv + x2 * sv;
          o2[n] = x2 * cv - x1 * sv;
          ss += o1[n] * o1[n] + o2[n] * o2[n];
        }
        ss += __shfl_xor(ss, 1); ss += __shfl_xor(ss, 2);
        ss += __shfl_xor(ss, 4); ss += __shfl_xor(ss, 8);
        float scn = rsqrtf(ss * (1.0f / 128.0f) + cEPS);
        if (bn < 16) {
          long base = (((long)b * cH + bn) * cS + s) * cD;
          #pragma unroll
          for (int n = 0; n < 4; ++n) {
            Qn[base + n * 16 + l15] = f2bf(o1[n] * scn);
            Qn[base + 64 + n * 16 + l15] = f2bf(o2[n] * scn);
          }
        } else {
          long base = ((long)b * cS + s) * cD;
          int xs = (s & 7) << 3;
          #pragma unroll
          for (int n = 0; n < 4; ++n) {
            Kn[base + ((n * 16 + l15) ^ xs)] = f2bf(o1[n] * scn);
            Kn[base + (((64 + n * 16 + l15)) ^ xs)] = f2bf(o2[n] * scn);
          }
        }
      }
  }
}

// -------- V transpose: Vn[b][s][d] -> Vt[b][d][s ^ ((d&7)<<3)] --------
__global__ __launch_bounds__(256) void vtrans(
    const unsigned short* __restrict__ Vn, unsigned short* __restrict__ Vt)
{
  __shared__ unsigned short Tl[64][72];
  const int t = threadIdx.x;
  const int st = blockIdx.x * 64, dt = blockIdx.y * 64, b = blockIdx.z;
  const unsigned short* Vb = Vn + (long)b * cS * cD;
  #pragma unroll
  for (int i = 0; i < 2; ++i) {
    int r = i * 32 + (t >> 3), c8 = (t & 7) * 8;
    *reinterpret_cast<uint4*>(&Tl[r][c8]) =
        *reinterpret_cast<const uint4*>(&Vb[(long)(st + r) * cD + dt + c8]);
  }
  __syncthreads();
  unsigned short* Vo = Vt + (long)b * cD * cS;
  #pragma unroll
  for (int i = 0; i < 2; ++i) {
    int d = i * 32 + (t >> 3), sb = (t & 7) * 8;
    unsigned short e[8];
    #pragma unroll
    for (int j = 0; j < 8; ++j) e[j] = Tl[sb + j][d];
    uint4 o;
    o.x = (unsigned)e[0] | ((unsigned)e[1] << 16);
    o.y = (unsigned)e[2] | ((unsigned)e[3] << 16);
    o.z = (unsigned)e[4] | ((unsigned)e[5] << 16);
    o.w = (unsigned)e[6] | ((unsigned)e[7] << 16);
    int dg = dt + d;
    *reinterpret_cast<uint4*>(&Vo[(long)dg * cS + st + (sb ^ ((dg & 7) << 3))]) = o;
  }
}

// -------- Flash attention (causal MQA), global_load_lds staging --------
__global__ __launch_bounds__(256) void attn2(
    const unsigned short* __restrict__ Qn,
    const unsigned short* __restrict__ Kn,   // swizzled
    const unsigned short* __restrict__ Vt,   // [b][d][s] swizzled
    unsigned short* __restrict__ O)          // [B*S][H*D] bf16
{
  __shared__ unsigned short lds[16384];      // Kl[64][128] | Vl[128][64]
  const int t = threadIdx.x, w = t >> 6, lane = t & 63;
  const int hi = lane >> 4, l15 = lane & 15;
  const int h = blockIdx.y, b = blockIdx.z;
  const unsigned short* Qb = Qn + (long)(b * cH + h) * cS * cD;
  const unsigned short* Kb = Kn + (long)b * cS * cD;
  const unsigned short* Vtb = Vt + (long)b * cD * cS;
  const int x3 = (l15 & 7) << 3;             // frag-read XOR (us units)
  const float sc2 = 0.08838834764831845f * 1.442695040888963f;

  #pragma unroll 1
  for (int pass = 0; pass < 2; ++pass) {
    const int qt = (pass == 0) ? blockIdx.x : 31 - blockIdx.x;
    const int q0 = qt * 64;
    const int qrow = q0 + w * 16 + l15;

    bf16x8 qf[4];
    #pragma unroll
    for (int kc = 0; kc < 4; ++kc)
      qf[kc] = *reinterpret_cast<const bf16x8*>(&Qb[(long)qrow * cD + kc * 32 + hi * 8]);

    f32x4 oacc[8] = {};
    float mrun = -1e30f, lrun = 0.f;
    const int nt = qt + 1;

    #pragma unroll 1
    for (int kt = 0; kt < nt; ++kt) {
      const int kv0 = kt * 64;
      __syncthreads();
      #pragma unroll
      for (int i = 0; i < 4; ++i) {
        int c = 4 * w + i;
        gl2l(Kb + (long)(kv0 + 4 * c + (lane >> 4)) * cD + (lane & 15) * 8,
             &lds[c * 512]);
        gl2l(Vtb + (long)(8 * c + (lane >> 3)) * cS + kv0 + (lane & 7) * 8,
             &lds[8192 + c * 512]);
      }
      __syncthreads();

      // QK^T swapped: st[n][r] = S^T[kv = n*16 + hi*4 + r][q]
      f32x4 st[4] = {};
      #pragma unroll
      for (int kc = 0; kc < 4; ++kc) {
        #pragma unroll
        for (int n = 0; n < 4; ++n) {
          bf16x8 kf = *reinterpret_cast<const bf16x8*>(
              &lds[(n * 16 + l15) * 128 + ((kc * 32 + hi * 8) ^ x3)]);
          st[n] = mfma16(kf, qf[kc], st[n]);
        }
      }

      // scale (+ causal mask on the diagonal tile only), log2 domain
      float p[4][4];
      if (kt == qt) {
        #pragma unroll
        for (int n = 0; n < 4; ++n)
          #pragma unroll
          for (int r = 0; r < 4; ++r) {
            int kv = kv0 + n * 16 + hi * 4 + r;
            p[n][r] = (kv <= qrow) ? st[n][r] * sc2 : -1e30f;
          }
      } else {
        #pragma unroll
        for (int n = 0; n < 4; ++n)
          #pragma unroll
          for (int r = 0; r < 4; ++r)
            p[n][r] = st[n][r] * sc2;
      }

      float pmax = p[0][0];
      #pragma unroll
      for (int n = 0; n < 4; ++n)
        #pragma unroll
        for (int r = 0; r < 4; ++r) pmax = fmaxf(pmax, p[n][r]);
      pmax = fmaxf(pmax, __shfl_xor(pmax, 16));
      pmax = fmaxf(pmax, __shfl_xor(pmax, 32));
      float mnew = fmaxf(mrun, pmax);
      float alpha = exp2f(mrun - mnew);
      mrun = mnew;

      float psum = 0.f;
      #pragma unroll
      for (int n = 0; n < 4; ++n)
        #pragma unroll
        for (int r = 0; r < 4; ++r) {
          p[n][r] = exp2f(p[n][r] - mnew);
          psum += p[n][r];
        }
      psum += __shfl_xor(psum, 16);
      psum += __shfl_xor(psum, 32);
      lrun = lrun * alpha + psum;

      #pragma unroll
      for (int n = 0; n < 8; ++n)
        #pragma unroll
        for (int r = 0; r < 4; ++r) oacc[n][r] *= alpha;

      unsigned pkl[4], pkh[4];
      #pragma unroll
      for (int n = 0; n < 4; ++n) {
        pkl[n] = pk2(p[n][0], p[n][1]);
        pkh[n] = pk2(p[n][2], p[n][3]);
      }

      // repack to PV A-fragment: pa[c][j] = P[q][c*32 + hi*8 + j]
      bf16x8 pa[2];
      #pragma unroll
      for (int c = 0; c < 2; ++c) {
        int ns = 2 * c + (hi >> 1);
        int no = 2 * c + ((hi >> 1) ^ 1);
        unsigned own0 = pkl[ns], own1 = pkh[ns];
        unsigned ot0 = pkl[no], ot1 = pkh[no];
        unsigned a160 = __shfl_xor(own0, 16), a161 = __shfl_xor(own1, 16);
        unsigned a320 = __shfl_xor(ot0, 32),  a321 = __shfl_xor(ot1, 32);
        unsigned a480 = __shfl_xor(ot0, 48),  a481 = __shfl_xor(ot1, 48);
        unsigned w0 = hi == 0 ? own0 : hi == 1 ? a480 : hi == 2 ? a320 : a160;
        unsigned w1 = hi == 0 ? own1 : hi == 1 ? a481 : hi == 2 ? a321 : a161;
        unsigned w2 = hi == 0 ? a160 : hi == 1 ? a320 : hi == 2 ? a480 : own0;
        unsigned w3 = hi == 0 ? a161 : hi == 1 ? a321 : hi == 2 ? a481 : own1;
        union { unsigned u[4]; bf16x8 v; } cvt;
        cvt.u[0] = w0; cvt.u[1] = w1; cvt.u[2] = w2; cvt.u[3] = w3;
        pa[c] = cvt.v;
      }

      // PV swapped: oacc[n2][r] = O^T[d = n2*16 + hi*4 + r][q]
      #pragma unroll
      for (int n2 = 0; n2 < 8; ++n2) {
        #pragma unroll
        for (int c = 0; c < 2; ++c) {
          bf16x8 vf = *reinterpret_cast<const bf16x8*>(
              &lds[8192 + (n2 * 16 + l15) * 64 + ((c * 32 + hi * 8) ^ x3)]);
          oacc[n2] = mfma16(vf, pa[c], oacc[n2]);
        }
      }
    }

    // epilogue: O^T -> O via per-wave LDS transpose, coalesced store
    __syncthreads();
    {
      float inv = 1.0f / lrun;
      unsigned short* Ol = &lds[w * 2176];   // [16][136]
      #pragma unroll
      for (int n2 = 0; n2 < 8; ++n2)
        #pragma unroll
        for (int r = 0; r < 4; ++r)
          Ol[l15 * 136 + n2 * 16 + hi * 4 + r] = f2bf(oacc[n2][r] * inv);
      __syncthreads();
      #pragma unroll
      for (int i = 0; i < 4; ++i) {
        int row = hi + 4 * i;
        uint4 ov = *reinterpret_cast<const uint4*>(&Ol[row * 136 + l15 * 8]);
        *reinterpret_cast<uint4*>(
            &O[(long)(b * cS + q0 + w * 16 + row) * (cH * cD) + h * cD + l15 * 8]) = ov;
      }
    }
  }
}

// -------- output GEMM (m97 structure), fp32 C --------
__global__ __launch_bounds__(256) void gemm_out(
    const unsigned short* __restrict__ A,    // Ob [4096][2048]
    const unsigned short* __restrict__ W,    // wob [2048][2048]
    float* __restrict__ C)
{
  __shared__ unsigned short lds[8192];
  const int t = threadIdx.x;
  const int bm = blockIdx.x, bn = blockIdx.y;
  const int lane = t & 63, w = t >> 6;
  const int wr = w >> 1, wc = w & 1, hi = lane >> 4, l15 = lane & 15;
  const long wbase = (long)bn * 128;

  f32x4 acc[4][4] = {};
  for (int k0 = 0; k0 < 2048; k0 += 32) {
    #pragma unroll
    for (int i = 0; i < 2; ++i) {
      int c = w + 4 * i;
      gl2l(A + (long)(bm * 128 + 16 * c + (lane >> 2)) * 2048 + k0 + (lane & 3) * 8,
           &lds[c * 512]);
      gl2l(W + (wbase + 16 * c + (lane >> 2)) * 2048 + k0 + (lane & 3) * 8,
           &lds[4096 + c * 512]);
    }
    __syncthreads();
    bf16x8 af[4], bff[4];
    #pragma unroll
    for (int m = 0; m < 4; ++m)
      af[m] = *reinterpret_cast<const bf16x8*>(&lds[(wr * 64 + m * 16 + l15) * 32 + hi * 8]);
    #pragma unroll
    for (int n = 0; n < 4; ++n)
      bff[n] = *reinterpret_cast<const bf16x8*>(&lds[4096 + (wc * 64 + n * 16 + l15) * 32 + hi * 8]);
    #pragma unroll
    for (int m = 0; m < 4; ++m)
      #pragma unroll
      for (int n = 0; n < 4; ++n)
        acc[m][n] = mfma16(af[m], bff[n], acc[m][n]);
    __syncthreads();
  }

  #pragma unroll
  for (int m = 0; m < 4; ++m) {
    int row = bm * 128 + wr * 64 + m * 16 + hi * 4;
    #pragma unroll
    for (int n = 0; n < 4; ++n) {
      int col = bn * 128 + wc * 64 + n * 16 + l15;
      #pragma unroll
      for (int r = 0; r < 4; ++r)
        C[(long)(row + r) * 2048 + col] = acc[m][n][r];
    }
  }
}

extern "C" void kernel_launch(void* const* d_in, const int* in_sizes, int n_in,
                              void* d_out, int out_size, void* d_ws, size_t ws_size,
                              hipStream_t stream) {
  const float* x    = (const float*)d_in[0];
  const float* cosb = (const float*)d_in[1];
  const float* sinb = (const float*)d_in[2];
  const float* wq   = (const float*)d_in[3];
  const float* wk   = (const float*)d_in[4];
  const float* wv   = (const float*)d_in[5];
  const float* wo   = (const float*)d_in[6];
  float* out = (float*)d_out;

  char* ws = (char*)d_ws;
  unsigned short* xb  = (unsigned short*)(ws);                 // 16,777,216 B
  unsigned short* wqb = (unsigned short*)(ws + 16777216);      //  8,388,608 B
  unsigned short* wkb = (unsigned short*)(ws + 25165824);      //    524,288 B
  unsigned short* wvb = (unsigned short*)(ws + 25690112);      //    524,288 B
  unsigned short* Qn  = (unsigned short*)(ws + 26214400);      // 16,777,216 B
  unsigned short* Kn  = (unsigned short*)(ws + 42991616);      //  1,048,576 B
  unsigned short* Vn  = (unsigned short*)(ws + 44040192);      //  1,048,576 B
  unsigned short* Vtg = (unsigned short*)(ws + 45088768);      //  1,048,576 B
  unsigned short* Ob  = (unsigned short*)ws;                   // alias xb (dead)
  unsigned short* wob = (unsigned short*)(ws + 16777216);      // alias wqb (dead)

  cvt_qkv<<<dim3(6400), 256, 0, stream>>>(x, wq, wk, wv, xb, wqb, wkb, wvb);
  gemm_qkv<<<dim3(32, 18), 256, 0, stream>>>(xb, wqb, wkb, wvb, cosb, sinb, Qn, Kn, Vn);
  vtrans<<<dim3(32, 2, 2), 256, 0, stream>>>(Vn, Vtg);
  cvt_wo<<<dim3(2048), 256, 0, stream>>>(wo, wob);
  attn2<<<dim3(16, 16, 2), 256, 0, stream>>>(Qn, Kn, Vtg, Ob);
  gemm_out<<<dim3(32, 16), 256, 0, stream>>>(Ob, wob, out);
}